// Round 2
// baseline (324.162 us; speedup 1.0000x reference)
//
#include <hip/hip_runtime.h>
#include <hip/hip_fp16.h>

#define IN_C 5
#define HID  128
#define OUTC 64

#define NBUCK_MAX 512     // buckets = ceil(n/256); n=100000 -> 391

typedef _Float16 f16x8 __attribute__((ext_vector_type(8)));
typedef float    f32x4 __attribute__((ext_vector_type(4)));

// ---------------- init: pack W2 for MFMA ----------------
__global__ void __launch_bounds__(256)
k_init(const float* __restrict__ W2, __half* __restrict__ W2p) {
    int i = blockIdx.x * 256 + threadIdx.x;   // 8192
    int j = i & 7;
    int lane = (i >> 3) & 63;
    int kk = (i >> 9) & 3;
    int nt = i >> 11;
    int k = kk * 32 + (lane >> 4) * 8 + j;
    int nn = nt * 16 + (lane & 15);
    W2p[i] = __float2half(W2[k * OUTC + nn]);
}

// ---------------- CSR build: flat global-atomic counting sort ----------------

__global__ void __launch_bounds__(256)
k_zero(int* __restrict__ cnt, int* __restrict__ bsum, int n) {
    int i = blockIdx.x * 256 + threadIdx.x;
    if (i < n) cnt[i] = 0;
    if (blockIdx.x < 2) bsum[blockIdx.x * 256 + threadIdx.x] = 0;
}

__global__ void __launch_bounds__(256)
k_deg(const int* __restrict__ dst, int* __restrict__ cnt, int E) {
    int i = blockIdx.x * 256 + threadIdx.x;   // one int4 = 4 edges
    if (i < (E >> 2)) {
        int4 d = ((const int4*)dst)[i];
        atomicAdd(&cnt[d.x], 1);
        atomicAdd(&cnt[d.y], 1);
        atomicAdd(&cnt[d.z], 1);
        atomicAdd(&cnt[d.w], 1);
    }
}

// per-256-node bucket sums (no atomics)
__global__ void __launch_bounds__(256)
k_bsum(const int* __restrict__ cnt, int* __restrict__ bsum, int n) {
    __shared__ int red[256];
    int b = blockIdx.x, t = threadIdx.x;
    int v = b * 256 + t;
    red[t] = (v < n) ? cnt[v] : 0;
    __syncthreads();
#pragma unroll
    for (int off = 128; off > 0; off >>= 1) {
        if (t < off) red[t] += red[t + off];
        __syncthreads();
    }
    if (t == 0) bsum[b] = red[0];
}

// rowptr/cur via (redundant 512-bucket scan) + (local 256 scan); also dinv + xs pack
__global__ void __launch_bounds__(256)
k_scan_xs(const int* __restrict__ bsum, const int* __restrict__ cnt,
          const float* __restrict__ x,
          int* __restrict__ rowptr, int* __restrict__ cur, float* __restrict__ dinv,
          __half* __restrict__ xs, int n, int nb) {
    __shared__ int sc[NBUCK_MAX];
    __shared__ int sc2[256];
    int b = blockIdx.x;
    int t = threadIdx.x;

    sc[t]       = (t < nb) ? bsum[t] : 0;
    sc[t + 256] = (t + 256 < nb) ? bsum[t + 256] : 0;
    __syncthreads();
#pragma unroll
    for (int off = 1; off < NBUCK_MAX; off <<= 1) {
        int a0 = (t >= off) ? sc[t - off] : 0;
        int a1 = (t + 256 >= off) ? sc[t + 256 - off] : 0;
        __syncthreads();
        sc[t] += a0; sc[t + 256] += a1;
        __syncthreads();
    }
    int ebase = (b == 0) ? 0 : sc[b - 1];

    int v = b * 256 + t;
    int h = (v < n) ? cnt[v] : 0;
    sc2[t] = h;
    __syncthreads();
#pragma unroll
    for (int off = 1; off < 256; off <<= 1) {
        int a = (t >= off) ? sc2[t - off] : 0;
        __syncthreads();
        sc2[t] += a;
        __syncthreads();
    }
    int rs = sc2[t] - h;

    if (v < n) {
        int rp = ebase + rs;
        rowptr[v] = rp;
        cur[v] = rp;
        float dv = rsqrtf(1.0f + (float)h);
        dinv[v] = dv;
        const float* xp = x + (size_t)v * IN_C;
        __half2 hh[4];
        hh[0] = __floats2half2_rn(xp[0] * dv, xp[1] * dv);
        hh[1] = __floats2half2_rn(xp[2] * dv, xp[3] * dv);
        hh[2] = __floats2half2_rn(xp[4] * dv, 0.f);
        hh[3] = __floats2half2_rn(0.f, 0.f);
        *(uint4*)(xs + (size_t)v * 8) = *(uint4*)hh;
    }
}

__global__ void __launch_bounds__(256)
k_scatter(const int* __restrict__ src, const int* __restrict__ dst,
          int* __restrict__ cur, int* __restrict__ col, int E) {
    int i = blockIdx.x * 256 + threadIdx.x;   // one int4 = 4 edges
    if (i < (E >> 2)) {
        int4 s = ((const int4*)src)[i];
        int4 d = ((const int4*)dst)[i];
        col[atomicAdd(&cur[d.x], 1)] = s.x;
        col[atomicAdd(&cur[d.y], 1)] = s.y;
        col[atomicAdd(&cur[d.z], 1)] = s.z;
        col[atomicAdd(&cur[d.w], 1)] = s.w;
    }
}

// ------- fused: layer-1 gather + gemm1+relu (VALU, W1 in LDS) + gemm2 (MFMA fp16) -------
#define NB 64
#define H1STRIDE 132   // 128 + 4 halves pad
__global__ void __launch_bounds__(256, 7)
k_fused(const __half* __restrict__ xs, const float* __restrict__ dinv,
        const int* __restrict__ rowptr, const int* __restrict__ cnt,
        const int* __restrict__ col,
        const float* __restrict__ W1, const float* __restrict__ b1,
        const __half* __restrict__ W2p, __half* __restrict__ g2, int n) {
    __shared__ __half sh_h1[NB * H1STRIDE];   // 16896 B, [node][k]
    __shared__ float sh_xa[NB * 9];           // 2304 B
    __shared__ float sh_dinv[NB];             // 256 B
    __shared__ int sh_start[NB], sh_len[NB];  // 512 B
    __shared__ __half2 sh_w1[IN_C * 64];      // 1280 B: [k][jp] j-pair of W1 col
    __shared__ float sh_b1[HID];              // 512 B   (total 21760 -> 7 blocks/CU)
    int t = threadIdx.x;
    int base = blockIdx.x * NB;

    // stage W1 (fp16 pairs) + b1 into LDS
    for (int idx = t; idx < IN_C * 64; idx += 256) {
        int k = idx >> 6, jp = idx & 63;
        float2 w = *(const float2*)(W1 + k * HID + 2 * jp);
        sh_w1[idx] = __floats2half2_rn(w.x, w.y);
    }
    if (t < HID) sh_b1[t] = b1[t];

    if (t < NB) {
        int v = base + t;
        if (v < n) {
            sh_start[t] = rowptr[v];
            sh_len[t]   = cnt[v];
            sh_dinv[t]  = dinv[v];
        } else {
            sh_start[t] = 0; sh_len[t] = 0; sh_dinv[t] = 0.f;
        }
    }
    __syncthreads();

    // Gather: 8 threads per node, 2 node-halves per thread, shfl-reduce over octet
    {
        int q = t & 7;
#pragma unroll
        for (int half = 0; half < 2; ++half) {
            int vl = (t >> 3) + half * 32;
            int v = base + vl;
            int start = sh_start[vl], len = sh_len[vl];
            float a0 = 0.f, a1 = 0.f, a2 = 0.f, a3 = 0.f, a4 = 0.f;
            if (q == 0 && v < n) {
                uint4 r = *(const uint4*)(xs + (size_t)v * 8);
                const __half2* h = (const __half2*)&r;
                float2 f0 = __half22float2(h[0]), f1 = __half22float2(h[1]), f2 = __half22float2(h[2]);
                a0 = f0.x; a1 = f0.y; a2 = f1.x; a3 = f1.y; a4 = f2.x;
            }
            for (int k = q; k < len; k += 8) {
                int s = col[start + k];
                uint4 r = *(const uint4*)(xs + (size_t)s * 8);
                const __half2* h = (const __half2*)&r;
                float2 f0 = __half22float2(h[0]), f1 = __half22float2(h[1]), f2 = __half22float2(h[2]);
                a0 += f0.x; a1 += f0.y; a2 += f1.x; a3 += f1.y; a4 += f2.x;
            }
#pragma unroll
            for (int d = 1; d <= 4; d <<= 1) {
                a0 += __shfl_down(a0, d, 64);
                a1 += __shfl_down(a1, d, 64);
                a2 += __shfl_down(a2, d, 64);
                a3 += __shfl_down(a3, d, 64);
                a4 += __shfl_down(a4, d, 64);
            }
            if (q == 0) {
                float* sx = sh_xa + vl * 9;
                sx[0] = a0; sx[1] = a1; sx[2] = a2; sx[3] = a3; sx[4] = a4;
            }
        }
    }
    __syncthreads();

    // Phase A (VALU, LDS-fed): h1[v][j] = relu(dinv[v]*dot(xa[v],W1[:,j]) + b1[j])
    {
        int v = t >> 2;
        const float* xa = sh_xa + v * 9;
        float x0 = xa[0], x1 = xa[1], x2 = xa[2], x3 = xa[3], x4 = xa[4];
        float dv = sh_dinv[v];
        __half* hrow = sh_h1 + v * H1STRIDE;
#pragma unroll
        for (int i = 0; i < 16; ++i) {
            int jp = (t & 3) + 4 * i;
            float2 w0 = __half22float2(sh_w1[jp]);
            float2 w1v = __half22float2(sh_w1[64 + jp]);
            float2 w2v = __half22float2(sh_w1[128 + jp]);
            float2 w3 = __half22float2(sh_w1[192 + jp]);
            float2 w4 = __half22float2(sh_w1[256 + jp]);
            float acc0 = x0 * w0.x + x1 * w1v.x + x2 * w2v.x + x3 * w3.x + x4 * w4.x;
            float acc1 = x0 * w0.y + x1 * w1v.y + x2 * w2v.y + x3 * w3.y + x4 * w4.y;
            int j0 = jp * 2;
            float2 bb = *(const float2*)(sh_b1 + j0);
            *(__half2*)(hrow + j0) =
                __floats2half2_rn(fmaxf(acc0 * dv + bb.x, 0.f), fmaxf(acc1 * dv + bb.y, 0.f));
        }
    }
    __syncthreads();

    // Phase B (MFMA): g2[v][j] = dinv[v] * (h1 @ W2)[v][j]
    {
        int w = t >> 6;
        int lane = t & 63;
        int quad = lane >> 4, nn = lane & 15;
        const __half* arow = sh_h1 + (size_t)(w * 16 + nn) * H1STRIDE + quad * 8;
        f16x8 afr[4];
#pragma unroll
        for (int kk = 0; kk < 4; ++kk)
            afr[kk] = *(const f16x8*)(arow + kk * 32);

        const f16x8* bp = (const f16x8*)W2p + lane;
#pragma unroll
        for (int nt = 0; nt < 4; ++nt) {
            f32x4 acc = {0.f, 0.f, 0.f, 0.f};
#pragma unroll
            for (int kk = 0; kk < 4; ++kk)
                acc = __builtin_amdgcn_mfma_f32_16x16x32_f16(
                    afr[kk], bp[(nt * 4 + kk) * 64], acc, 0, 0, 0);
#pragma unroll
            for (int r = 0; r < 4; ++r) {
                int vl = w * 16 + quad * 4 + r;
                int v = base + vl;
                if (v < n)
                    g2[(size_t)v * OUTC + nt * 16 + nn] =
                        __float2half(acc[r] * sh_dinv[vl]);
            }
        }
    }
}

// ---------------- layer 2 aggregation ----------------
// 8-lane group per destination node (8 nodes/wave, 32/block).
// - no shuffle-reduce tree, no idle epilogue lanes (all 64 lanes compute+store)
// - f16->f32 accumulate via v_fma_mix_f32 (1 inst per feature instead of cvt+add)
// - unroll-2 with two accumulator banks

#define MIX_LO(A, W) \
    asm("v_fma_mix_f32 %0, %1, %2, %0 op_sel:[0,0,0] op_sel_hi:[1,0,0]" \
        : "+v"(A) : "v"(W), "v"(one))
#define MIX_HI(A, W) \
    asm("v_fma_mix_f32 %0, %1, %2, %0 op_sel:[1,0,0] op_sel_hi:[1,0,0]" \
        : "+v"(A) : "v"(W), "v"(one))

#define ACC8(P, R)            \
    do {                      \
        MIX_LO(P##0, (R).x);  \
        MIX_HI(P##1, (R).x);  \
        MIX_LO(P##2, (R).y);  \
        MIX_HI(P##3, (R).y);  \
        MIX_LO(P##4, (R).z);  \
        MIX_HI(P##5, (R).z);  \
        MIX_LO(P##6, (R).w);  \
        MIX_HI(P##7, (R).w);  \
    } while (0)

__global__ void __launch_bounds__(256)
k_agg2(const __half* __restrict__ g2, const float* __restrict__ dinv,
       const int* __restrict__ rowptr, const int* __restrict__ cnt,
       const int* __restrict__ col, const float* __restrict__ b2,
       float* __restrict__ out, int n) {
    int t = threadIdx.x;
    int g = t >> 3;              // group 0..31 in block = one destination node
    int oct = t & 7;             // feature octet: 8 halves = 16B per lane
    int v = blockIdx.x * 32 + g;
    if (v >= n) return;

    int start = rowptr[v], len = cnt[v];
    float one = 1.0f;

    float a0 = 0.f, a1 = 0.f, a2 = 0.f, a3 = 0.f,
          a4 = 0.f, a5 = 0.f, a6 = 0.f, a7 = 0.f;
    float c0 = 0.f, c1 = 0.f, c2 = 0.f, c3 = 0.f,
          c4 = 0.f, c5 = 0.f, c6 = 0.f, c7 = 0.f;

    int it = 0;
    for (; it + 2 <= len; it += 2) {
        int s0 = col[start + it];
        int s1 = col[start + it + 1];
        uint4 r0 = *(const uint4*)(g2 + ((size_t)s0 << 6) + (oct << 3));
        uint4 r1 = *(const uint4*)(g2 + ((size_t)s1 << 6) + (oct << 3));
        ACC8(a, r0);
        ACC8(c, r1);
    }
    if (it < len) {
        int s0 = col[start + it];
        uint4 r0 = *(const uint4*)(g2 + ((size_t)s0 << 6) + (oct << 3));
        ACC8(a, r0);
    }

    // self-loop term
    {
        uint4 rs = *(const uint4*)(g2 + ((size_t)v << 6) + (oct << 3));
        ACC8(a, rs);
    }

    a0 += c0; a1 += c1; a2 += c2; a3 += c3;
    a4 += c4; a5 += c5; a6 += c6; a7 += c7;

    float dv = dinv[v];
    const float* bp = b2 + (oct << 3);
    float4 bb0 = *(const float4*)bp;
    float4 bb1 = *(const float4*)(bp + 4);

    float4 o0 = make_float4(dv * a0 + bb0.x, dv * a1 + bb0.y,
                            dv * a2 + bb0.z, dv * a3 + bb0.w);
    float4 o1 = make_float4(dv * a4 + bb1.x, dv * a5 + bb1.y,
                            dv * a6 + bb1.z, dv * a7 + bb1.w);
    float4* op = (float4*)(out + ((size_t)v << 6) + (oct << 3));
    op[0] = o0;
    op[1] = o1;
}

// ---------------- launch ----------------

extern "C" void kernel_launch(void* const* d_in, const int* in_sizes, int n_in,
                              void* d_out, int out_size, void* d_ws, size_t ws_size,
                              hipStream_t stream) {
    const float* x  = (const float*)d_in[0];
    const int*   ei = (const int*)d_in[1];
    const float* W1 = (const float*)d_in[2];
    const float* b1 = (const float*)d_in[3];
    const float* W2 = (const float*)d_in[4];
    const float* b2 = (const float*)d_in[5];
    float*       out = (float*)d_out;

    const int n = in_sizes[0] / IN_C;   // 100000
    const int E = in_sizes[1] / 2;      // 1600000
    const int* src = ei;
    const int* dst = ei + E;
    const int nbuck = (n + 255) / 256;  // 391

    char* ws = (char*)d_ws;
    size_t off = 0;
    int* cnt    = (int*)(ws + off); off += (size_t)n * 4;
    int* rowptr = (int*)(ws + off); off += (size_t)n * 4;
    int* cur    = (int*)(ws + off); off += (size_t)n * 4;
    int* col    = (int*)(ws + off); off += (size_t)E * 4;
    float* dinv = (float*)(ws + off); off += (size_t)n * 4;
    __half* xs  = (__half*)(ws + off); off += (size_t)n * 8 * 2;
    __half* g2  = (__half*)(ws + off); off += (size_t)n * OUTC * 2;
    __half* W2p = (__half*)(ws + off); off += (size_t)HID * OUTC * 2;
    int* bsum   = (int*)(ws + off); off += NBUCK_MAX * 4;

    const int B = 256;
    const int e4blocks = ((E >> 2) + B - 1) / B;   // 1563

    k_init<<<(HID * OUTC) / B, B, 0, stream>>>(W2, W2p);
    k_zero<<<nbuck, B, 0, stream>>>(cnt, bsum, n);
    k_deg<<<e4blocks, B, 0, stream>>>(dst, cnt, E);
    k_bsum<<<nbuck, B, 0, stream>>>(cnt, bsum, n);
    k_scan_xs<<<nbuck, B, 0, stream>>>(bsum, cnt, x, rowptr, cur, dinv, xs, n, nbuck);
    k_scatter<<<e4blocks, B, 0, stream>>>(src, dst, cur, col, E);

    k_fused<<<(n + NB - 1) / NB, B, 0, stream>>>(xs, dinv, rowptr, cnt, col,
                                                 W1, b1, W2p, g2, n);
    k_agg2<<<(n + 31) / 32, B, 0, stream>>>(g2, dinv, rowptr, cnt, col, b2, out, n);
}

// Round 3
// 168.361 us; speedup vs baseline: 1.9254x; 1.9254x over previous
//
#include <hip/hip_runtime.h>
#include <hip/hip_fp16.h>

#define IN_C 5
#define HID  128
#define OUTC 64

#define NBUCK_MAX 512     // buckets = ceil(n/256); n=100000 -> 391
#define BCAP      4800    // per-bucket capacity (mean 4092, sigma ~64; +11 sigma)
#define BIN_GRID  512
#define BIN_PER   3328    // 13*256 >= ceil(E/BIN_GRID)=3125
#define BIN_ITERS 13

typedef _Float16 f16x8 __attribute__((ext_vector_type(8)));
typedef float    f32x4 __attribute__((ext_vector_type(4)));

// ---------------- init: zero bucket counters + pack W2 for MFMA ----------------
__global__ void __launch_bounds__(256)
k_init(const float* __restrict__ W2, __half* __restrict__ W2p,
       int* __restrict__ bucket_cnt) {
    if (blockIdx.x < 2) bucket_cnt[blockIdx.x * 256 + threadIdx.x] = 0;
    int i = blockIdx.x * 256 + threadIdx.x;   // 8192
    int j = i & 7;
    int lane = (i >> 3) & 63;
    int kk = (i >> 9) & 3;
    int nt = i >> 11;
    int k = kk * 32 + (lane >> 4) * 8 + j;
    int nn = nt * 16 + (lane & 15);
    W2p[i] = __float2half(W2[k * OUTC + nn]);
}

// ---------------- CSR build: 2-pass LDS counting sort, 256-node buckets ----------------
__global__ void __launch_bounds__(256)
k_bin(const int* __restrict__ src, const int* __restrict__ dst,
      int* __restrict__ bucket_cnt, unsigned* __restrict__ binned, int E) {
    __shared__ int hist[NBUCK_MAX], base[NBUCK_MAX], lstart[NBUCK_MAX], cur[NBUCK_MAX];
    __shared__ unsigned staged[BIN_PER];
    __shared__ unsigned short sbuck[BIN_PER];
    int t = threadIdx.x;
    hist[t] = 0; hist[t + 256] = 0;
    __syncthreads();
    int per = (E + gridDim.x - 1) / gridDim.x;
    int lo = blockIdx.x * per, hi = min(E, lo + per);
    int ds[BIN_ITERS], ss[BIN_ITERS];
#pragma unroll
    for (int i = 0; i < BIN_ITERS; ++i) {
        int e = lo + t + i * 256;
        if (e < hi) {
            int d = dst[e];
            ds[i] = d; ss[i] = src[e];
            atomicAdd(&hist[d >> 8], 1);
        } else ds[i] = -1;
    }
    __syncthreads();
    if (hist[t] > 0)       base[t] = atomicAdd(&bucket_cnt[t], hist[t]);
    if (hist[t + 256] > 0) base[t + 256] = atomicAdd(&bucket_cnt[t + 256], hist[t + 256]);
    lstart[t] = hist[t]; lstart[t + 256] = hist[t + 256];
    __syncthreads();
#pragma unroll
    for (int off = 1; off < NBUCK_MAX; off <<= 1) {
        int a0 = (t >= off) ? lstart[t - off] : 0;
        int a1 = (t + 256 >= off) ? lstart[t + 256 - off] : 0;
        __syncthreads();
        lstart[t] += a0; lstart[t + 256] += a1;
        __syncthreads();
    }
    {
        int e0 = lstart[t] - hist[t];
        int e1 = lstart[t + 256] - hist[t + 256];
        __syncthreads();
        lstart[t] = e0; lstart[t + 256] = e1;
        cur[t] = e0; cur[t + 256] = e1;
    }
    __syncthreads();
#pragma unroll
    for (int i = 0; i < BIN_ITERS; ++i) {
        if (ds[i] >= 0) {
            int d = ds[i];
            int b = d >> 8;
            int pos = atomicAdd(&cur[b], 1);
            staged[pos] = ((unsigned)ss[i] << 8) | (unsigned)(d & 255);
            sbuck[pos] = (unsigned short)b;
        }
    }
    __syncthreads();
    int mtot = hi - lo;
    for (int s = t; s < mtot; s += 256) {
        int b = sbuck[s];
        binned[(size_t)b * BCAP + base[b] + (s - lstart[b])] = staged[s];
    }
}

// Pass B: one block per 256-node bucket. LDS-staged col emission (coalesced).
__global__ void __launch_bounds__(256)
k_csr(const unsigned* __restrict__ binned, const int* __restrict__ bucket_cnt,
      const float* __restrict__ x,
      int* __restrict__ rowptr, int* __restrict__ cnt, float* __restrict__ dinv,
      __half* __restrict__ xs, int* __restrict__ col, int n, int nb) {
    __shared__ int sc[NBUCK_MAX];
    __shared__ int hist[256], sc2[256], cur[256];
    __shared__ int staged[BCAP];
    int b = blockIdx.x;
    int t = threadIdx.x;

    sc[t]       = (t < nb) ? bucket_cnt[t] : 0;
    sc[t + 256] = (t + 256 < nb) ? bucket_cnt[t + 256] : 0;
    __syncthreads();
#pragma unroll
    for (int off = 1; off < NBUCK_MAX; off <<= 1) {
        int a0 = (t >= off) ? sc[t - off] : 0;
        int a1 = (t + 256 >= off) ? sc[t + 256 - off] : 0;
        __syncthreads();
        sc[t] += a0; sc[t + 256] += a1;
        __syncthreads();
    }
    int m = bucket_cnt[b];
    int ebase = (b == 0) ? 0 : sc[b - 1];
    const unsigned* bin = binned + (size_t)b * BCAP;

    hist[t] = 0;
    __syncthreads();
    for (int e = t; e < m; e += 256)
        atomicAdd(&hist[bin[e] & 255], 1);
    __syncthreads();

    int h = hist[t];
    sc2[t] = h;
    __syncthreads();
#pragma unroll
    for (int off = 1; off < 256; off <<= 1) {
        int a = (t >= off) ? sc2[t - off] : 0;
        __syncthreads();
        sc2[t] += a;
        __syncthreads();
    }
    int rs = sc2[t] - h;
    cur[t] = rs;

    int v = b * 256 + t;
    if (v < n) {
        rowptr[v] = ebase + rs;
        cnt[v] = h;
        float dv = rsqrtf(1.0f + (float)h);
        dinv[v] = dv;
        const float* xp = x + (size_t)v * IN_C;
        __half2 hh[4];
        hh[0] = __floats2half2_rn(xp[0] * dv, xp[1] * dv);
        hh[1] = __floats2half2_rn(xp[2] * dv, xp[3] * dv);
        hh[2] = __floats2half2_rn(xp[4] * dv, 0.f);
        hh[3] = __floats2half2_rn(0.f, 0.f);
        *(uint4*)(xs + (size_t)v * 8) = *(uint4*)hh;
    }
    __syncthreads();
    for (int e = t; e < m; e += 256) {
        unsigned p = bin[e];
        int pos = atomicAdd(&cur[p & 255], 1);
        staged[pos] = (int)(p >> 8);
    }
    __syncthreads();
    for (int e = t; e < m; e += 256)
        col[ebase + e] = staged[e];
}

// ------- fused: layer-1 gather + gemm1+relu (VALU, W1 in LDS) + gemm2 (MFMA fp16) -------
#define NB 64
#define H1STRIDE 132   // 128 + 4 halves pad
__global__ void __launch_bounds__(256, 7)
k_fused(const __half* __restrict__ xs, const float* __restrict__ dinv,
        const int* __restrict__ rowptr, const int* __restrict__ cnt,
        const int* __restrict__ col,
        const float* __restrict__ W1, const float* __restrict__ b1,
        const __half* __restrict__ W2p, __half* __restrict__ g2, int n) {
    __shared__ __half sh_h1[NB * H1STRIDE];   // 16896 B, [node][k]
    __shared__ float sh_xa[NB * 9];           // 2304 B
    __shared__ float sh_dinv[NB];             // 256 B
    __shared__ int sh_start[NB], sh_len[NB];  // 512 B
    __shared__ __half2 sh_w1[IN_C * 64];      // 1280 B: [k][jp] j-pair of W1 col
    __shared__ float sh_b1[HID];              // 512 B   (total 21760 -> 7 blocks/CU)
    int t = threadIdx.x;
    int base = blockIdx.x * NB;

    // stage W1 (fp16 pairs) + b1 into LDS
    for (int idx = t; idx < IN_C * 64; idx += 256) {
        int k = idx >> 6, jp = idx & 63;
        float2 w = *(const float2*)(W1 + k * HID + 2 * jp);
        sh_w1[idx] = __floats2half2_rn(w.x, w.y);
    }
    if (t < HID) sh_b1[t] = b1[t];

    if (t < NB) {
        int v = base + t;
        if (v < n) {
            sh_start[t] = rowptr[v];
            sh_len[t]   = cnt[v];
            sh_dinv[t]  = dinv[v];
        } else {
            sh_start[t] = 0; sh_len[t] = 0; sh_dinv[t] = 0.f;
        }
    }
    __syncthreads();

    // Gather: 8 threads per node, 2 node-halves per thread, shfl-reduce over octet
    {
        int q = t & 7;
#pragma unroll
        for (int half = 0; half < 2; ++half) {
            int vl = (t >> 3) + half * 32;
            int v = base + vl;
            int start = sh_start[vl], len = sh_len[vl];
            float a0 = 0.f, a1 = 0.f, a2 = 0.f, a3 = 0.f, a4 = 0.f;
            if (q == 0 && v < n) {
                uint4 r = *(const uint4*)(xs + (size_t)v * 8);
                const __half2* h = (const __half2*)&r;
                float2 f0 = __half22float2(h[0]), f1 = __half22float2(h[1]), f2 = __half22float2(h[2]);
                a0 = f0.x; a1 = f0.y; a2 = f1.x; a3 = f1.y; a4 = f2.x;
            }
            for (int k = q; k < len; k += 8) {
                int s = col[start + k];
                uint4 r = *(const uint4*)(xs + (size_t)s * 8);
                const __half2* h = (const __half2*)&r;
                float2 f0 = __half22float2(h[0]), f1 = __half22float2(h[1]), f2 = __half22float2(h[2]);
                a0 += f0.x; a1 += f0.y; a2 += f1.x; a3 += f1.y; a4 += f2.x;
            }
#pragma unroll
            for (int d = 1; d <= 4; d <<= 1) {
                a0 += __shfl_down(a0, d, 64);
                a1 += __shfl_down(a1, d, 64);
                a2 += __shfl_down(a2, d, 64);
                a3 += __shfl_down(a3, d, 64);
                a4 += __shfl_down(a4, d, 64);
            }
            if (q == 0) {
                float* sx = sh_xa + vl * 9;
                sx[0] = a0; sx[1] = a1; sx[2] = a2; sx[3] = a3; sx[4] = a4;
            }
        }
    }
    __syncthreads();

    // Phase A (VALU, LDS-fed): h1[v][j] = relu(dinv[v]*dot(xa[v],W1[:,j]) + b1[j])
    {
        int v = t >> 2;
        const float* xa = sh_xa + v * 9;
        float x0 = xa[0], x1 = xa[1], x2 = xa[2], x3 = xa[3], x4 = xa[4];
        float dv = sh_dinv[v];
        __half* hrow = sh_h1 + v * H1STRIDE;
#pragma unroll
        for (int i = 0; i < 16; ++i) {
            int jp = (t & 3) + 4 * i;
            float2 w0 = __half22float2(sh_w1[jp]);
            float2 w1v = __half22float2(sh_w1[64 + jp]);
            float2 w2v = __half22float2(sh_w1[128 + jp]);
            float2 w3 = __half22float2(sh_w1[192 + jp]);
            float2 w4 = __half22float2(sh_w1[256 + jp]);
            float acc0 = x0 * w0.x + x1 * w1v.x + x2 * w2v.x + x3 * w3.x + x4 * w4.x;
            float acc1 = x0 * w0.y + x1 * w1v.y + x2 * w2v.y + x3 * w3.y + x4 * w4.y;
            int j0 = jp * 2;
            float2 bb = *(const float2*)(sh_b1 + j0);
            *(__half2*)(hrow + j0) =
                __floats2half2_rn(fmaxf(acc0 * dv + bb.x, 0.f), fmaxf(acc1 * dv + bb.y, 0.f));
        }
    }
    __syncthreads();

    // Phase B (MFMA): g2[v][j] = dinv[v] * (h1 @ W2)[v][j]
    {
        int w = t >> 6;
        int lane = t & 63;
        int quad = lane >> 4, nn = lane & 15;
        const __half* arow = sh_h1 + (size_t)(w * 16 + nn) * H1STRIDE + quad * 8;
        f16x8 afr[4];
#pragma unroll
        for (int kk = 0; kk < 4; ++kk)
            afr[kk] = *(const f16x8*)(arow + kk * 32);

        const f16x8* bp = (const f16x8*)W2p + lane;
#pragma unroll
        for (int nt = 0; nt < 4; ++nt) {
            f32x4 acc = {0.f, 0.f, 0.f, 0.f};
#pragma unroll
            for (int kk = 0; kk < 4; ++kk)
                acc = __builtin_amdgcn_mfma_f32_16x16x32_f16(
                    afr[kk], bp[(nt * 4 + kk) * 64], acc, 0, 0, 0);
#pragma unroll
            for (int r = 0; r < 4; ++r) {
                int vl = w * 16 + quad * 4 + r;
                int v = base + vl;
                if (v < n)
                    g2[(size_t)v * OUTC + nt * 16 + nn] =
                        __float2half(acc[r] * sh_dinv[vl]);
            }
        }
    }
}

// ---------------- layer 2 aggregation ----------------
// 8-lane group per destination node (8 nodes/wave, 32/block).
// - no shuffle-reduce tree, no idle epilogue lanes (all 64 lanes compute+store)
// - f16->f32 accumulate via v_fma_mix_f32 (1 inst per feature instead of cvt+add)
// - unroll-4 with four accumulator banks: 4 row-loads + 32 FMA chains in
//   flight per lane (deeper MLP against L3 gather latency)

#define MIX_LO(A, W) \
    asm("v_fma_mix_f32 %0, %1, %2, %0 op_sel:[0,0,0] op_sel_hi:[1,0,0]" \
        : "+v"(A) : "v"(W), "v"(one))
#define MIX_HI(A, W) \
    asm("v_fma_mix_f32 %0, %1, %2, %0 op_sel:[1,0,0] op_sel_hi:[1,0,0]" \
        : "+v"(A) : "v"(W), "v"(one))

#define ACC8(P, R)            \
    do {                      \
        MIX_LO(P##0, (R).x);  \
        MIX_HI(P##1, (R).x);  \
        MIX_LO(P##2, (R).y);  \
        MIX_HI(P##3, (R).y);  \
        MIX_LO(P##4, (R).z);  \
        MIX_HI(P##5, (R).z);  \
        MIX_LO(P##6, (R).w);  \
        MIX_HI(P##7, (R).w);  \
    } while (0)

__global__ void __launch_bounds__(256)
k_agg2(const __half* __restrict__ g2, const float* __restrict__ dinv,
       const int* __restrict__ rowptr, const int* __restrict__ cnt,
       const int* __restrict__ col, const float* __restrict__ b2,
       float* __restrict__ out, int n) {
    int t = threadIdx.x;
    int g = t >> 3;              // group 0..31 in block = one destination node
    int oct = t & 7;             // feature octet: 8 halves = 16B per lane
    int v = blockIdx.x * 32 + g;
    if (v >= n) return;

    int start = rowptr[v], len = cnt[v];
    float one = 1.0f;
    const __half* gb = g2 + (oct << 3);

    float a0 = 0.f, a1 = 0.f, a2 = 0.f, a3 = 0.f,
          a4 = 0.f, a5 = 0.f, a6 = 0.f, a7 = 0.f;
    float c0 = 0.f, c1 = 0.f, c2 = 0.f, c3 = 0.f,
          c4 = 0.f, c5 = 0.f, c6 = 0.f, c7 = 0.f;
    float e0 = 0.f, e1 = 0.f, e2 = 0.f, e3 = 0.f,
          e4 = 0.f, e5 = 0.f, e6 = 0.f, e7 = 0.f;
    float f0 = 0.f, f1 = 0.f, f2 = 0.f, f3 = 0.f,
          f4 = 0.f, f5 = 0.f, f6 = 0.f, f7 = 0.f;

    int it = 0;
    for (; it + 4 <= len; it += 4) {
        int s0 = col[start + it];
        int s1 = col[start + it + 1];
        int s2 = col[start + it + 2];
        int s3 = col[start + it + 3];
        uint4 r0 = *(const uint4*)(gb + ((size_t)s0 << 6));
        uint4 r1 = *(const uint4*)(gb + ((size_t)s1 << 6));
        uint4 r2 = *(const uint4*)(gb + ((size_t)s2 << 6));
        uint4 r3 = *(const uint4*)(gb + ((size_t)s3 << 6));
        ACC8(a, r0);
        ACC8(c, r1);
        ACC8(e, r2);
        ACC8(f, r3);
    }
    if (it + 2 <= len) {
        int s0 = col[start + it];
        int s1 = col[start + it + 1];
        uint4 r0 = *(const uint4*)(gb + ((size_t)s0 << 6));
        uint4 r1 = *(const uint4*)(gb + ((size_t)s1 << 6));
        ACC8(a, r0);
        ACC8(c, r1);
        it += 2;
    }
    if (it < len) {
        int s0 = col[start + it];
        uint4 r0 = *(const uint4*)(gb + ((size_t)s0 << 6));
        ACC8(e, r0);
    }

    // self-loop term
    {
        uint4 rs = *(const uint4*)(gb + ((size_t)v << 6));
        ACC8(f, rs);
    }

    a0 += c0; a1 += c1; a2 += c2; a3 += c3;
    a4 += c4; a5 += c5; a6 += c6; a7 += c7;
    e0 += f0; e1 += f1; e2 += f2; e3 += f3;
    e4 += f4; e5 += f5; e6 += f6; e7 += f7;
    a0 += e0; a1 += e1; a2 += e2; a3 += e3;
    a4 += e4; a5 += e5; a6 += e6; a7 += e7;

    float dv = dinv[v];
    const float* bp = b2 + (oct << 3);
    float4 bb0 = *(const float4*)bp;
    float4 bb1 = *(const float4*)(bp + 4);

    float4 o0 = make_float4(dv * a0 + bb0.x, dv * a1 + bb0.y,
                            dv * a2 + bb0.z, dv * a3 + bb0.w);
    float4 o1 = make_float4(dv * a4 + bb1.x, dv * a5 + bb1.y,
                            dv * a6 + bb1.z, dv * a7 + bb1.w);
    float4* op = (float4*)(out + ((size_t)v << 6) + (oct << 3));
    op[0] = o0;
    op[1] = o1;
}

// ---------------- launch ----------------

extern "C" void kernel_launch(void* const* d_in, const int* in_sizes, int n_in,
                              void* d_out, int out_size, void* d_ws, size_t ws_size,
                              hipStream_t stream) {
    const float* x  = (const float*)d_in[0];
    const int*   ei = (const int*)d_in[1];
    const float* W1 = (const float*)d_in[2];
    const float* b1 = (const float*)d_in[3];
    const float* W2 = (const float*)d_in[4];
    const float* b2 = (const float*)d_in[5];
    float*       out = (float*)d_out;

    const int n = in_sizes[0] / IN_C;   // 100000
    const int E = in_sizes[1] / 2;      // 1600000
    const int* src = ei;
    const int* dst = ei + E;
    const int nbuck = (n + 255) / 256;  // 391

    char* ws = (char*)d_ws;
    size_t off = 0;
    int* cnt         = (int*)(ws + off); off += (size_t)n * 4;
    int* rowptr      = (int*)(ws + off); off += (size_t)n * 4;
    int* col         = (int*)(ws + off); off += (size_t)E * 4;
    float* dinv      = (float*)(ws + off); off += (size_t)n * 4;
    __half* xs       = (__half*)(ws + off); off += (size_t)n * 8 * 2;
    __half* g2       = (__half*)(ws + off); off += (size_t)n * OUTC * 2;
    __half* W2p      = (__half*)(ws + off); off += (size_t)HID * OUTC * 2;
    int* bucket_cnt  = (int*)(ws + off); off += NBUCK_MAX * 4;
    unsigned* binned = (unsigned*)(ws + off); off += (size_t)NBUCK_MAX * BCAP * 4;

    const int B = 256;

    k_init<<<(HID * OUTC) / B, B, 0, stream>>>(W2, W2p, bucket_cnt);
    k_bin<<<BIN_GRID, B, 0, stream>>>(src, dst, bucket_cnt, binned, E);
    k_csr<<<nbuck, B, 0, stream>>>(binned, bucket_cnt, x,
                                   rowptr, cnt, dinv, xs, col, n, nbuck);

    k_fused<<<(n + NB - 1) / NB, B, 0, stream>>>(xs, dinv, rowptr, cnt, col,
                                                 W1, b1, W2p, g2, n);
    k_agg2<<<(n + 31) / 32, B, 0, stream>>>(g2, dinv, rowptr, cnt, col, b2, out, n);
}